// Round 7
// baseline (809.438 us; speedup 1.0000x reference)
//
#include <hip/hip_runtime.h>
#include <hip/hip_fp16.h>

#define HIDDIM 256
#define NHEADS 8

struct half4 { __half2 a, b; };

// ---------------- GEMM: C[M,N] = act(A[M,K] @ W[K,N] + bias[N]) ----------------
template <int HALF_OUT>
__global__ __launch_bounds__(256) void gemm_bias_act(
    const float* __restrict__ A, const float* __restrict__ W,
    const float* __restrict__ bias, void* __restrict__ Cv,
    int M, int N, int K, int act) {
  __shared__ float As[16][65];
  __shared__ float Bs[16][64];
  const int tid = threadIdx.x;
  const int bm = blockIdx.y * 64, bn = blockIdx.x * 64;
  const int tx = tid & 15, ty = tid >> 4;
  float acc[4][4] = {};
  for (int k0 = 0; k0 < K; k0 += 16) {
    {
      const int m = tid >> 2;
      const int k = (tid & 3) * 4;
      const int gm = bm + m;
      float4 v = make_float4(0.f, 0.f, 0.f, 0.f);
      if (gm < M) v = *(const float4*)(A + (size_t)gm * K + k0 + k);
      As[k + 0][m] = v.x; As[k + 1][m] = v.y; As[k + 2][m] = v.z; As[k + 3][m] = v.w;
    }
    {
      const int n = (tid & 15) * 4;
      const int k = tid >> 4;
      *(float4*)&Bs[k][n] = *(const float4*)(W + (size_t)(k0 + k) * N + bn + n);
    }
    __syncthreads();
    #pragma unroll
    for (int kk = 0; kk < 16; ++kk) {
      float a[4], b[4];
      #pragma unroll
      for (int i = 0; i < 4; ++i) a[i] = As[kk][ty * 4 + i];
      #pragma unroll
      for (int j = 0; j < 4; ++j) b[j] = Bs[kk][tx * 4 + j];
      #pragma unroll
      for (int i = 0; i < 4; ++i)
        #pragma unroll
        for (int j = 0; j < 4; ++j) acc[i][j] = fmaf(a[i], b[j], acc[i][j]);
    }
    __syncthreads();
  }
  #pragma unroll
  for (int i = 0; i < 4; ++i) {
    const int gm = bm + ty * 4 + i;
    if (gm >= M) continue;
    float v[4];
    #pragma unroll
    for (int j = 0; j < 4; ++j) {
      const int gn = bn + tx * 4 + j;
      v[j] = acc[i][j] + bias[gn];
      if (act == 1 && v[j] < 0.f) v[j] = 0.f;
    }
    if (HALF_OUT) {
      half4 hv;
      hv.a = __floats2half2_rn(v[0], v[1]);
      hv.b = __floats2half2_rn(v[2], v[3]);
      *(half4*)((__half*)Cv + (size_t)gm * N + bn + tx * 4) = hv;
    } else {
      *(float4*)((float*)Cv + (size_t)gm * N + bn + tx * 4) =
          make_float4(v[0], v[1], v[2], v[3]);
    }
  }
}

// ---------------- CSR build (by destination; stores SRC node id) ----------------
__global__ __launch_bounds__(256) void count_deg(
    const int* __restrict__ ei, int* __restrict__ deg, int E, int Nn) {
  const int t = blockIdx.x * blockDim.x + threadIdx.x;
  const int ET = E + Nn;
  if (t >= ET) return;
  const int dst = (t < E) ? ei[E + t] : (t - E);
  atomicAdd(&deg[dst], 1);
}

__global__ __launch_bounds__(1024) void scan_deg(
    const int* __restrict__ deg, int* __restrict__ rowptr, int Nn) {
  __shared__ int wsum[16];
  __shared__ int carry_s;
  const int tid = threadIdx.x;
  const int wid = tid >> 6, lane = tid & 63;
  if (tid == 0) { carry_s = 0; rowptr[0] = 0; }
  __syncthreads();
  for (int base = 0; base < Nn; base += 1024) {
    const int i = base + tid;
    int s = (i < Nn) ? deg[i] : 0;
    #pragma unroll
    for (int off = 1; off < 64; off <<= 1) {
      int t = __shfl_up(s, off);
      if (lane >= off) s += t;
    }
    if (lane == 63) wsum[wid] = s;
    __syncthreads();
    if (wid == 0 && lane < 16) {
      int ws = wsum[lane];
      #pragma unroll
      for (int off = 1; off < 16; off <<= 1) {
        int t = __shfl_up(ws, off);
        if (lane >= off) ws += t;
      }
      wsum[lane] = ws;
    }
    __syncthreads();
    const int prefix = (wid > 0 ? wsum[wid - 1] : 0) + carry_s;
    if (i < Nn) rowptr[i + 1] = s + prefix;
    __syncthreads();
    if (tid == 0) carry_s += wsum[15];
    __syncthreads();
  }
}

__global__ __launch_bounds__(256) void fill_csr(
    const int* __restrict__ ei, const int* __restrict__ rowptr,
    int* __restrict__ cursor, int* __restrict__ csr, int E, int Nn) {
  const int t = blockIdx.x * blockDim.x + threadIdx.x;
  const int ET = E + Nn;
  if (t >= ET) return;
  int src, dst;
  if (t < E) { src = ei[t]; dst = ei[E + t]; }
  else { src = t - E; dst = t - E; }
  const int pos = atomicAdd(&cursor[dst], 1);
  csr[rowptr[dst] + pos] = src;
}

// ---------------- fused GATv2: one BLOCK per node, 4 waves split the edge list ----------------
// lane covers channels [4*lane,4*lane+4); head h = lane>>3
// each wave keeps a private online-softmax (m,d,acc); merged exactly in LDS.
template <int MODE>
__global__ __launch_bounds__(256) void node_gat(
    const __half* __restrict__ xl, const float* __restrict__ xr,
    const int* __restrict__ rowptr, const int* __restrict__ csr,
    const float* __restrict__ att, const float* __restrict__ bias,
    const float* __restrict__ lng, const float* __restrict__ lnb,
    const int* __restrict__ batch, float* __restrict__ pooled,
    float* __restrict__ counts, float* __restrict__ outp, int Nn) {
  const int n = blockIdx.x;
  const int wid = threadIdx.x >> 6;
  const int lane = threadIdx.x & 63;
  const int r0 = rowptr[n], r1 = rowptr[n + 1];
  const int deg = r1 - r0;
  const int chunk = (deg + 3) >> 2;
  const int s0 = r0 + wid * chunk;
  const int s1 = min(s0 + chunk, r1);

  const half4* __restrict__ xlv = (const half4*)xl;
  const float4 xr4 = *(const float4*)(xr + (size_t)n * HIDDIM + lane * 4);
  const float4 at4 = *(const float4*)(att + lane * 4);

  float m = -1e30f, d = 0.f;
  float4 acc = make_float4(0.f, 0.f, 0.f, 0.f);

  for (int base = s0; base < s1; base += 64) {
    const int cnt = s1 - base < 64 ? s1 - base : 64;   // wave-uniform
    // one coalesced load covers up to 64 edge indices for this wave
    const int cvec = csr[base + (lane < cnt ? lane : cnt - 1)];
    for (int k0 = 0; k0 < cnt; k0 += 4) {
      const int j1 = k0 + 1 < cnt ? k0 + 1 : cnt - 1;
      const int j2 = k0 + 2 < cnt ? k0 + 2 : cnt - 1;
      const int j3 = k0 + 3 < cnt ? k0 + 3 : cnt - 1;
      const int i0 = __shfl(cvec, k0);
      const int i1 = __shfl(cvec, j1);
      const int i2 = __shfl(cvec, j2);
      const int i3 = __shfl(cvec, j3);
      const half4 r0h = xlv[(size_t)i0 * (HIDDIM / 4) + lane];
      const half4 r1h = xlv[(size_t)i1 * (HIDDIM / 4) + lane];
      const half4 r2h = xlv[(size_t)i2 * (HIDDIM / 4) + lane];
      const half4 r3h = xlv[(size_t)i3 * (HIDDIM / 4) + lane];

      float4 a0, a1, a2, a3;
      {
        float2 f;
        f = __half22float2(r0h.a); a0.x = f.x; a0.y = f.y;
        f = __half22float2(r0h.b); a0.z = f.x; a0.w = f.y;
        f = __half22float2(r1h.a); a1.x = f.x; a1.y = f.y;
        f = __half22float2(r1h.b); a1.z = f.x; a1.w = f.y;
        f = __half22float2(r2h.a); a2.x = f.x; a2.y = f.y;
        f = __half22float2(r2h.b); a2.z = f.x; a2.w = f.y;
        f = __half22float2(r3h.a); a3.x = f.x; a3.y = f.y;
        f = __half22float2(r3h.b); a3.z = f.x; a3.w = f.y;
      }
      float s0v, s1v, s2v, s3v;
      {
        float v;
        v = a0.x + xr4.x; v = v >= 0.f ? v : 0.2f * v; s0v = v * at4.x;
        v = a0.y + xr4.y; v = v >= 0.f ? v : 0.2f * v; s0v = fmaf(v, at4.y, s0v);
        v = a0.z + xr4.z; v = v >= 0.f ? v : 0.2f * v; s0v = fmaf(v, at4.z, s0v);
        v = a0.w + xr4.w; v = v >= 0.f ? v : 0.2f * v; s0v = fmaf(v, at4.w, s0v);
        v = a1.x + xr4.x; v = v >= 0.f ? v : 0.2f * v; s1v = v * at4.x;
        v = a1.y + xr4.y; v = v >= 0.f ? v : 0.2f * v; s1v = fmaf(v, at4.y, s1v);
        v = a1.z + xr4.z; v = v >= 0.f ? v : 0.2f * v; s1v = fmaf(v, at4.z, s1v);
        v = a1.w + xr4.w; v = v >= 0.f ? v : 0.2f * v; s1v = fmaf(v, at4.w, s1v);
        v = a2.x + xr4.x; v = v >= 0.f ? v : 0.2f * v; s2v = v * at4.x;
        v = a2.y + xr4.y; v = v >= 0.f ? v : 0.2f * v; s2v = fmaf(v, at4.y, s2v);
        v = a2.z + xr4.z; v = v >= 0.f ? v : 0.2f * v; s2v = fmaf(v, at4.z, s2v);
        v = a2.w + xr4.w; v = v >= 0.f ? v : 0.2f * v; s2v = fmaf(v, at4.w, s2v);
        v = a3.x + xr4.x; v = v >= 0.f ? v : 0.2f * v; s3v = v * at4.x;
        v = a3.y + xr4.y; v = v >= 0.f ? v : 0.2f * v; s3v = fmaf(v, at4.y, s3v);
        v = a3.z + xr4.z; v = v >= 0.f ? v : 0.2f * v; s3v = fmaf(v, at4.z, s3v);
        v = a3.w + xr4.w; v = v >= 0.f ? v : 0.2f * v; s3v = fmaf(v, at4.w, s3v);
      }
      s0v += __shfl_xor(s0v, 1); s0v += __shfl_xor(s0v, 2); s0v += __shfl_xor(s0v, 4);
      s1v += __shfl_xor(s1v, 1); s1v += __shfl_xor(s1v, 2); s1v += __shfl_xor(s1v, 4);
      s2v += __shfl_xor(s2v, 1); s2v += __shfl_xor(s2v, 2); s2v += __shfl_xor(s2v, 4);
      s3v += __shfl_xor(s3v, 1); s3v += __shfl_xor(s3v, 2); s3v += __shfl_xor(s3v, 4);
      if (k0 + 1 >= cnt) s1v = -1e30f;
      if (k0 + 2 >= cnt) s2v = -1e30f;
      if (k0 + 3 >= cnt) s3v = -1e30f;

      const float mb = fmaxf(fmaxf(fmaxf(s0v, s1v), fmaxf(s2v, s3v)), m);
      const float scale = __expf(m - mb);
      const float w0 = __expf(s0v - mb);
      const float w1 = __expf(s1v - mb);
      const float w2 = __expf(s2v - mb);
      const float w3 = __expf(s3v - mb);
      d = fmaf(d, scale, (w0 + w1) + (w2 + w3));
      acc.x = fmaf(acc.x, scale, fmaf(w0, a0.x, fmaf(w1, a1.x, fmaf(w2, a2.x, w3 * a3.x))));
      acc.y = fmaf(acc.y, scale, fmaf(w0, a0.y, fmaf(w1, a1.y, fmaf(w2, a2.y, w3 * a3.y))));
      acc.z = fmaf(acc.z, scale, fmaf(w0, a0.z, fmaf(w1, a1.z, fmaf(w2, a2.z, w3 * a3.z))));
      acc.w = fmaf(acc.w, scale, fmaf(w0, a0.w, fmaf(w1, a1.w, fmaf(w2, a2.w, w3 * a3.w))));
      m = mb;
    }
  }

  // ---- merge the 4 per-wave partials in LDS ----
  __shared__ float sm[4][64];
  __shared__ float sd[4][64];
  __shared__ float4 sa[4][64];
  sm[wid][lane] = m;
  sd[wid][lane] = d;
  sa[wid][lane] = acc;
  __syncthreads();
  if (wid != 0) return;

  const float m0 = sm[0][lane], m1 = sm[1][lane], m2 = sm[2][lane], m3 = sm[3][lane];
  const float ms = fmaxf(fmaxf(m0, m1), fmaxf(m2, m3));
  const float e0 = __expf(m0 - ms), e1 = __expf(m1 - ms);
  const float e2 = __expf(m2 - ms), e3 = __expf(m3 - ms);
  const float dt = sd[0][lane] * e0 + sd[1][lane] * e1 + sd[2][lane] * e2 + sd[3][lane] * e3;
  const float4 A0 = sa[0][lane], A1 = sa[1][lane], A2 = sa[2][lane], A3 = sa[3][lane];
  const float inv_d = 1.f / dt;
  float4 am;
  am.x = (A0.x * e0 + A1.x * e1 + A2.x * e2 + A3.x * e3) * inv_d;
  am.y = (A0.y * e0 + A1.y * e1 + A2.y * e2 + A3.y * e3) * inv_d;
  am.z = (A0.z * e0 + A1.z * e1 + A2.z * e2 + A3.z * e3) * inv_d;
  am.w = (A0.w * e0 + A1.w * e1 + A2.w * e2 + A3.w * e3) * inv_d;

  const float4 bb = *(const float4*)(bias + lane * 4);
  float t0 = am.x + bb.x; t0 = t0 > 0.f ? t0 : 0.f;
  float t1 = am.y + bb.y; t1 = t1 > 0.f ? t1 : 0.f;
  float t2 = am.z + bb.z; t2 = t2 > 0.f ? t2 : 0.f;
  float t3 = am.w + bb.w; t3 = t3 > 0.f ? t3 : 0.f;

  if (MODE == 0) {
    float s = t0 + t1 + t2 + t3;
    #pragma unroll
    for (int mm = 1; mm < 64; mm <<= 1) s += __shfl_xor(s, mm);
    const float mu = s * (1.f / HIDDIM);
    const float d0 = t0 - mu, d1 = t1 - mu, d2 = t2 - mu, d3 = t3 - mu;
    float q = d0 * d0 + d1 * d1 + d2 * d2 + d3 * d3;
    #pragma unroll
    for (int mm = 1; mm < 64; mm <<= 1) q += __shfl_xor(q, mm);
    const float inv = rsqrtf(q * (1.f / HIDDIM) + 1e-5f);
    const float4 g4 = *(const float4*)(lng + lane * 4);
    const float4 b4 = *(const float4*)(lnb + lane * 4);
    float4 o;
    o.x = d0 * inv * g4.x + b4.x;
    o.y = d1 * inv * g4.y + b4.y;
    o.z = d2 * inv * g4.z + b4.z;
    o.w = d3 * inv * g4.w + b4.w;
    *(float4*)(outp + (size_t)n * HIDDIM + lane * 4) = o;
  } else {
    const int g = batch[n];
    float* p = pooled + (size_t)g * HIDDIM + lane * 4;
    atomicAdd(p + 0, t0);
    atomicAdd(p + 1, t1);
    atomicAdd(p + 2, t2);
    atomicAdd(p + 3, t3);
    if (lane == 0) atomicAdd(&counts[g], 1.f);
  }
}

// ---------------- head MLP ----------------
__global__ __launch_bounds__(256) void head_kernel(
    const float* __restrict__ pooled, const float* __restrict__ counts,
    const float* __restrict__ h1w, const float* __restrict__ h1b,
    const float* __restrict__ h2w, const float* __restrict__ h2b,
    float* __restrict__ out, int G, int H1, int OUT) {
  __shared__ float P[16][HIDDIM];
  __shared__ float Hh[16][128];
  const int tid = threadIdx.x;
  for (int i = tid; i < G * HIDDIM; i += 256) {
    const int g = i / HIDDIM, c = i % HIDDIM;
    float cnt = counts[g];
    if (cnt < 1.f) cnt = 1.f;
    P[g][c] = pooled[i] / cnt;
  }
  __syncthreads();
  for (int i = tid; i < G * H1; i += 256) {
    const int g = i / H1, j = i % H1;
    float s = h1b[j];
    for (int k = 0; k < HIDDIM; ++k) s = fmaf(P[g][k], h1w[k * H1 + j], s);
    Hh[g][j] = s > 0.f ? s : 0.f;
  }
  __syncthreads();
  for (int i = tid; i < G * OUT; i += 256) {
    const int g = i / OUT, o = i % OUT;
    float s = h2b[o];
    for (int k = 0; k < H1; ++k) s = fmaf(Hh[g][k], h2w[k * OUT + o], s);
    out[i] = s;
  }
}

extern "C" void kernel_launch(void* const* d_in, const int* in_sizes, int n_in,
                              void* d_out, int out_size, void* d_ws, size_t ws_size,
                              hipStream_t stream) {
  const float* x = (const float*)d_in[0];
  const int* ei = (const int*)d_in[1];
  const int* batch = (const int*)d_in[2];
  const float* enc_w = (const float*)d_in[3];
  const float* enc_b = (const float*)d_in[4];
  const float* g_wl[2] = {(const float*)d_in[5], (const float*)d_in[11]};
  const float* g_bl[2] = {(const float*)d_in[6], (const float*)d_in[12]};
  const float* g_wr[2] = {(const float*)d_in[7], (const float*)d_in[13]};
  const float* g_br[2] = {(const float*)d_in[8], (const float*)d_in[14]};
  const float* g_att[2] = {(const float*)d_in[9], (const float*)d_in[15]};
  const float* g_bias[2] = {(const float*)d_in[10], (const float*)d_in[16]};
  const float* ln_g = (const float*)d_in[17];
  const float* ln_b = (const float*)d_in[18];
  const float* h1_w = (const float*)d_in[19];
  const float* h1_b = (const float*)d_in[20];
  const float* h2_w = (const float*)d_in[21];
  const float* h2_b = (const float*)d_in[22];
  float* out = (float*)d_out;

  const int N = in_sizes[2];          // 20000
  const int E = in_sizes[1] / 2;      // 320000
  const int DIN = in_sizes[0] / N;    // 128
  const int ET = E + N;
  const int H1 = in_sizes[20];        // 128
  const int OUT = in_sizes[22];       // 2
  const int G = out_size / OUT;       // 16

  float* ws = (float*)d_ws;
  const size_t NH = (size_t)N * HIDDIM;
  float* h0 = ws;
  float* xr = h0 + NH;
  __half* xl = (__half*)(xr + NH);                          // NH halves
  float* pooled = (float*)((char*)xl + NH * sizeof(__half));// [G,256]
  float* counts = pooled + (size_t)G * HIDDIM;              // [G]
  int* deg = (int*)(counts + G);                            // [N]
  int* rowptr = deg + N;                                    // [N+1]
  int* cursor = rowptr + (N + 1);                           // [N]
  int* csr = cursor + N;                                    // [ET]

  const dim3 blk(256);
  const dim3 gemm_grid(HIDDIM / 64, (N + 63) / 64);
  const int eb = (ET + 255) / 256;

  // CSR build (graph identical for both layers)
  hipMemsetAsync(deg, 0, (size_t)N * sizeof(int), stream);
  hipMemsetAsync(cursor, 0, (size_t)N * sizeof(int), stream);
  hipMemsetAsync(pooled, 0, ((size_t)G * HIDDIM + G) * sizeof(float), stream);
  count_deg<<<eb, blk, 0, stream>>>(ei, deg, E, N);
  scan_deg<<<1, 1024, 0, stream>>>(deg, rowptr, N);
  fill_csr<<<eb, blk, 0, stream>>>(ei, rowptr, cursor, csr, E, N);

  // encoder
  gemm_bias_act<0><<<gemm_grid, blk, 0, stream>>>(x, enc_w, enc_b, h0, N, HIDDIM, DIN, 1);

  for (int L = 0; L < 2; ++L) {
    gemm_bias_act<1><<<gemm_grid, blk, 0, stream>>>(h0, g_wl[L], g_bl[L], xl, N, HIDDIM, HIDDIM, 0);
    gemm_bias_act<0><<<gemm_grid, blk, 0, stream>>>(h0, g_wr[L], g_br[L], xr, N, HIDDIM, HIDDIM, 0);
    if (L == 0) {
      node_gat<0><<<N, blk, 0, stream>>>(xl, xr, rowptr, csr, g_att[0], g_bias[0],
                                         ln_g, ln_b, nullptr, nullptr, nullptr, h0, N);
    } else {
      node_gat<1><<<N, blk, 0, stream>>>(xl, xr, rowptr, csr, g_att[1], g_bias[1],
                                         nullptr, nullptr, batch, pooled, counts, nullptr, N);
    }
  }
  head_kernel<<<1, blk, 0, stream>>>(pooled, counts, h1_w, h1_b, h2_w, h2_b, out, G, H1, OUT);
}